// Round 13
// baseline (435.936 us; speedup 1.0000x reference)
//
#include <hip/hip_runtime.h>
#include <stdint.h>

#define D_IN   2048
#define D_OUT  512

typedef __bf16 bf16;
typedef bf16     bf16x8 __attribute__((ext_vector_type(8)));
typedef float    f32x4  __attribute__((ext_vector_type(4)));
typedef uint32_t u32x4  __attribute__((ext_vector_type(4)));

#define GLP(p)  (const __attribute__((address_space(1))) void*)(p)
#define LDSP(p) (__attribute__((address_space(3))) void*)(p)

// ---------------- degree count ----------------
__global__ void k_count(const int* __restrict__ dstv, int* __restrict__ cnt, int E) {
    int e = blockIdx.x * blockDim.x + threadIdx.x;
    if (e < E) atomicAdd(&cnt[dstv[e]], 1);
}

// ---------------- hierarchical exclusive scan (+ dis, + cur=0) ----------------
__global__ __launch_bounds__(1024) void k_scan1(const int* __restrict__ cnt,
                                                int* __restrict__ offs,
                                                int* __restrict__ bsum,
                                                float* __restrict__ dis,
                                                int* __restrict__ cur, int n) {
    __shared__ int wsum[16], wbase[16];
    const int tid = threadIdx.x, lane = tid & 63, wv = tid >> 6;
    int i = blockIdx.x * 1024 + tid;
    int v = (i < n) ? cnt[i] : 0;
    int x = v;
    #pragma unroll
    for (int d = 1; d < 64; d <<= 1) {
        int y = __shfl_up(x, d);
        if (lane >= d) x += y;
    }
    if (lane == 63) wsum[wv] = x;
    __syncthreads();
    if (tid < 16) {
        int s = 0;
        for (int j = 0; j < tid; ++j) s += wsum[j];
        wbase[tid] = s;
    }
    __syncthreads();
    if (i < n) {
        offs[i] = wbase[wv] + x - v;            // block-local exclusive
        dis[i]  = rsqrtf((float)(v + 1));
        cur[i]  = 0;
    }
    if (tid == 0) bsum[blockIdx.x] = wbase[15] + wsum[15];
}

__global__ void k_scan2(int* __restrict__ bsum, int nb) {
    int t = threadIdx.x;
    if (nb <= 64) {
        int v = (t < nb) ? bsum[t] : 0;
        int x = v;
        #pragma unroll
        for (int d = 1; d < 64; d <<= 1) {
            int y = __shfl_up(x, d);
            if (t >= d) x += y;
        }
        if (t < nb) bsum[t] = x - v;   // exclusive
    } else if (t == 0) {
        int run = 0;
        for (int j = 0; j < nb; ++j) { int v = bsum[j]; bsum[j] = run; run += v; }
    }
}

// ---------------- CSR fill (offs = local + bsum); also nrm[p] = dis[src] ----------------
__global__ void k_fill(const int* __restrict__ srcv, const int* __restrict__ dstv,
                       const int* __restrict__ offs, const int* __restrict__ bsum,
                       const float* __restrict__ dis, int* __restrict__ cur,
                       int* __restrict__ csr, float* __restrict__ nrm, int E) {
    int e = blockIdx.x * blockDim.x + threadIdx.x;
    if (e < E) {
        int d = dstv[e];
        int s = srcv[e];
        int p = offs[d] + bsum[d >> 10] + atomicAdd(&cur[d], 1);
        csr[p] = s;
        nrm[p] = dis[s];
    }
}

// ---------------- weight transpose + bf16 cast: wt[n][k] = (bf16)W[k][n] ----------------
__global__ void k_wt(const float* __restrict__ W, uint16_t* __restrict__ wt) {
    __shared__ float t[32][33];
    int kb = blockIdx.x * 32, nb = blockIdx.y * 32;
    int tx = threadIdx.x, ty = threadIdx.y;
    #pragma unroll
    for (int i = 0; i < 32; i += 8)
        t[ty + i][tx] = W[(size_t)(kb + ty + i) * D_OUT + nb + tx];
    __syncthreads();
    bf16* o = (bf16*)wt;
    #pragma unroll
    for (int i = 0; i < 32; i += 8)
        o[(size_t)(nb + ty + i) * D_IN + kb + tx] = (bf16)t[tx][ty + i];
}

// ---------------- fused GEMM: H[M][512] = (bf16)X[M][2048](fp32) * W ----------------
// R11 structure with B moved OUT of LDS: WT is 2MB (L2/L3-resident), so B
// fragments load directly global->regs (16B/lane coalesced, L2-hit), issued
// before the barrier so their latency hides under the A-DMA drain.
// Per K-step: 8 gload_lds (A only, was 12), 16 ds_reads (was 24), LDS 32KB.
// A path unchanged: fp32 staged via global_load_lds, 2 x 32-col halves,
// XOR involution u^(row&7) on pre-swizzled source + LDS read.
__global__ __launch_bounds__(256, 3) void k_gemm(const float* __restrict__ X,
                                                 const uint16_t* __restrict__ WT,
                                                 uint16_t* __restrict__ H, int M) {
    __shared__ float lsA[2][128 * 32];  // 32 KB
    // bijective chunked XCD swizzle: one m-panel's 4 n-blocks -> same XCD
    const int nwg = gridDim.x;
    const int b = blockIdx.x;
    const int q = nwg >> 3, r = nwg & 7;
    const int xcd = b & 7, lo = b >> 3;
    const int g = (xcd < r) ? (xcd * (q + 1) + lo) : (r * (q + 1) + (xcd - r) * q + lo);
    const int m0 = (g >> 2) * 128;
    const int n0 = (g & 3) * 128;
    const int tid = threadIdx.x;
    const int w = tid >> 6, lane = tid & 63;
    const int wr = w >> 1, wc = w & 1;
    const int lr = lane & 15, lk = lane >> 4;

    f32x4 acc[4][4];
    #pragma unroll
    for (int m = 0; m < 4; m++)
        #pragma unroll
        for (int n = 0; n < 4; n++) acc[m][n] = (f32x4)(0.0f);

    const float* aSrc[2][4];
    #pragma unroll
    for (int j = 0; j < 4; j++) {
        int c = w * 4 + j;
        int uidx = c * 64 + lane;
        int row = uidx >> 3, u = uidx & 7;
        int lrow = row;
        if (m0 + row >= M) lrow = (M - 1) - m0;   // clamp: valid data staged, stores masked
        const float* rbase = X + (size_t)(m0 + lrow) * D_IN;
        #pragma unroll
        for (int h = 0; h < 2; h++)
            aSrc[h][j] = rbase + h * 32 + (u ^ (row & 7)) * 4;
    }
    // B fragment base pointers: row = n0 + wc*64 + n*16 + lr, k-offset lk*8
    const uint16_t* bPtr[4];
    #pragma unroll
    for (int n = 0; n < 4; n++)
        bPtr[n] = WT + (size_t)(n0 + wc * 64 + n * 16 + lr) * D_IN + lk * 8;

    for (int k0 = 0; k0 < D_IN; k0 += 64) {
        #pragma unroll
        for (int h = 0; h < 2; h++)
            #pragma unroll
            for (int j = 0; j < 4; j++)
                __builtin_amdgcn_global_load_lds(GLP(aSrc[h][j] + k0),
                                                 LDSP(lsA[h] + (w * 4 + j) * 256), 16, 0, 0);
        // B fragments for this K-step: direct global->regs (L2-hit), issued
        // before the barrier so the drain covers their latency too.
        bf16x8 bF[4][2];
        #pragma unroll
        for (int n = 0; n < 4; n++)
            #pragma unroll
            for (int kk = 0; kk < 2; kk++)
                bF[n][kk] = *(const bf16x8*)(bPtr[n] + k0 + kk * 32);
        __syncthreads();

        #pragma unroll
        for (int kk = 0; kk < 2; kk++) {
            bf16x8 aF[4];
            #pragma unroll
            for (int m = 0; m < 4; m++) {
                int row = wr * 64 + m * 16 + lr;
                const float* base = lsA[kk] + row * 32;
                f32x4 a0 = *(const f32x4*)(base + (((2 * lk)    ) ^ (row & 7)) * 4);
                f32x4 a1 = *(const f32x4*)(base + (((2 * lk) + 1) ^ (row & 7)) * 4);
                bf16x8 af;
                af[0] = (bf16)a0[0]; af[1] = (bf16)a0[1]; af[2] = (bf16)a0[2]; af[3] = (bf16)a0[3];
                af[4] = (bf16)a1[0]; af[5] = (bf16)a1[1]; af[6] = (bf16)a1[2]; af[7] = (bf16)a1[3];
                aF[m] = af;
            }
            #pragma unroll
            for (int m = 0; m < 4; m++)
                #pragma unroll
                for (int n = 0; n < 4; n++)
                    acc[m][n] = __builtin_amdgcn_mfma_f32_16x16x32_bf16(aF[m], bF[n][kk], acc[m][n], 0, 0, 0);
        }
        __syncthreads();
    }

    // epilogue: C/D layout col=lane&15, row=(lane>>4)*4+reg; store bf16
    #pragma unroll
    for (int m = 0; m < 4; m++) {
        int rbase = m0 + wr * 64 + m * 16 + lk * 4;
        #pragma unroll
        for (int n = 0; n < 4; n++) {
            int col = n0 + wc * 64 + n * 16 + lr;
            #pragma unroll
            for (int j = 0; j < 4; j++) {
                int row = rbase + j;
                if (row < M) {
                    bf16 t = (bf16)acc[m][n][j];
                    H[(size_t)row * D_OUT + col] = __builtin_bit_cast(uint16_t, t);
                }
            }
        }
    }
}

// ---------------- aggregation + bias + log_softmax, one wave per node ----------------
// edge loop unrolled x2; nrm[] read linearly (no random dis gather)
__global__ __launch_bounds__(256) void k_agg(const uint16_t* __restrict__ h,
                                             const int* __restrict__ csr,
                                             const float* __restrict__ nrm,
                                             const int* __restrict__ offs,
                                             const int* __restrict__ bsum,
                                             const int* __restrict__ cnt,
                                             const float* __restrict__ dis,
                                             const float* __restrict__ bias,
                                             float* __restrict__ out, int N) {
    const int wv = threadIdx.x >> 6, lane = threadIdx.x & 63;
    const int i = blockIdx.x * 4 + wv;
    if (i >= N) return;
    const float di = dis[i];
    float acc[8];
    {
        u32x4 v = *(const u32x4*)(h + (size_t)i * D_OUT + lane * 8);
        float s2 = di * di;
        #pragma unroll
        for (int k = 0; k < 4; k++) {
            acc[2 * k]     = __builtin_bit_cast(float, v[k] << 16) * s2;
            acc[2 * k + 1] = __builtin_bit_cast(float, v[k] & 0xffff0000u) * s2;
        }
    }
    const int o = offs[i] + bsum[i >> 10], c = cnt[i];
    int e = o;
    for (; e + 2 <= o + c; e += 2) {
        int s0 = csr[e], s1 = csr[e + 1];
        float w0 = di * nrm[e], w1 = di * nrm[e + 1];
        u32x4 v0 = *(const u32x4*)(h + (size_t)s0 * D_OUT + lane * 8);
        u32x4 v1 = *(const u32x4*)(h + (size_t)s1 * D_OUT + lane * 8);
        #pragma unroll
        for (int k = 0; k < 4; k++) {
            acc[2 * k]     += __builtin_bit_cast(float, v0[k] << 16) * w0;
            acc[2 * k + 1] += __builtin_bit_cast(float, v0[k] & 0xffff0000u) * w0;
        }
        #pragma unroll
        for (int k = 0; k < 4; k++) {
            acc[2 * k]     += __builtin_bit_cast(float, v1[k] << 16) * w1;
            acc[2 * k + 1] += __builtin_bit_cast(float, v1[k] & 0xffff0000u) * w1;
        }
    }
    if (e < o + c) {
        int s0 = csr[e];
        float w0 = di * nrm[e];
        u32x4 v0 = *(const u32x4*)(h + (size_t)s0 * D_OUT + lane * 8);
        #pragma unroll
        for (int k = 0; k < 4; k++) {
            acc[2 * k]     += __builtin_bit_cast(float, v0[k] << 16) * w0;
            acc[2 * k + 1] += __builtin_bit_cast(float, v0[k] & 0xffff0000u) * w0;
        }
    }
    {
        const f32x4* bp = (const f32x4*)(bias + lane * 8);
        f32x4 b0 = bp[0], b1 = bp[1];
        #pragma unroll
        for (int k = 0; k < 4; k++) { acc[k] += b0[k]; acc[4 + k] += b1[k]; }
    }
    float mx = acc[0];
    #pragma unroll
    for (int k = 1; k < 8; k++) mx = fmaxf(mx, acc[k]);
    #pragma unroll
    for (int d = 1; d < 64; d <<= 1) mx = fmaxf(mx, __shfl_xor(mx, d));
    float se = 0.f;
    #pragma unroll
    for (int k = 0; k < 8; k++) se += expf(acc[k] - mx);
    #pragma unroll
    for (int d = 1; d < 64; d <<= 1) se += __shfl_xor(se, d);
    float lse = mx + logf(se);
    f32x4 o0, o1;
    #pragma unroll
    for (int k = 0; k < 4; k++) { o0[k] = acc[k] - lse; o1[k] = acc[4 + k] - lse; }
    f32x4* op = (f32x4*)(out + (size_t)i * D_OUT + lane * 8);
    op[0] = o0; op[1] = o1;
}

// ---------------- launch ----------------
extern "C" void kernel_launch(void* const* d_in, const int* in_sizes, int n_in,
                              void* d_out, int out_size, void* d_ws, size_t ws_size,
                              hipStream_t stream) {
    const float* x    = (const float*)d_in[0];
    const int*   ei   = (const int*)d_in[1];
    const float* W    = (const float*)d_in[2];
    const float* bias = (const float*)d_in[3];
    float* out = (float*)d_out;

    const int N = in_sizes[0] / D_IN;     // 50000
    const int E = in_sizes[1] / 2;        // 400000
    const int* srcv = ei;
    const int* dstv = ei + E;

    char* p = (char*)d_ws;
    auto carve = [&](size_t b) { void* r = (void*)p; p += (b + 255) & ~(size_t)255; return r; };
    uint16_t* h    = (uint16_t*)carve((size_t)N * D_OUT * 2);            // 51.2 MB
    uint16_t* wt   = (uint16_t*)carve((size_t)D_OUT * D_IN * 2);         // 2 MB
    int*      cnt  = (int*)carve((size_t)N * 4);
    int*      cur  = (int*)carve((size_t)N * 4);
    float*    dis  = (float*)carve((size_t)N * 4);
    int*      offs = (int*)carve((size_t)N * 4);
    int*      csr  = (int*)carve((size_t)E * 4);
    float*    nrm  = (float*)carve((size_t)E * 4);
    int*      bsum = (int*)carve(1024 * 4);

    hipMemsetAsync(cnt, 0, (size_t)N * 4, stream);

    k_wt<<<dim3(D_IN / 32, D_OUT / 32), dim3(32, 8), 0, stream>>>(W, wt);
    k_count<<<(E + 255) / 256, 256, 0, stream>>>(dstv, cnt, E);
    const int nb = (N + 1023) / 1024;
    k_scan1<<<nb, 1024, 0, stream>>>(cnt, offs, bsum, dis, cur, N);
    k_scan2<<<1, 64, 0, stream>>>(bsum, nb);
    k_fill<<<(E + 255) / 256, 256, 0, stream>>>(srcv, dstv, offs, bsum, dis, cur, csr, nrm, E);

    k_gemm<<<((N + 127) / 128) * 4, 256, 0, stream>>>(x, wt, h, N);

    k_agg<<<(N + 3) / 4, 256, 0, stream>>>(h, csr, nrm, offs, bsum, cnt, dis, bias, out, N);
}

// Round 14
// 323.097 us; speedup vs baseline: 1.3492x; 1.3492x over previous
//
#include <hip/hip_runtime.h>
#include <stdint.h>

#define D_IN   2048
#define D_OUT  512

typedef __bf16 bf16;
typedef bf16     bf16x8 __attribute__((ext_vector_type(8)));
typedef float    f32x4  __attribute__((ext_vector_type(4)));
typedef uint32_t u32x4  __attribute__((ext_vector_type(4)));

#define GLP(p)  (const __attribute__((address_space(1))) void*)(p)
#define LDSP(p) (__attribute__((address_space(3))) void*)(p)

// ---------------- degree count ----------------
__global__ void k_count(const int* __restrict__ dstv, int* __restrict__ cnt, int E) {
    int e = blockIdx.x * blockDim.x + threadIdx.x;
    if (e < E) atomicAdd(&cnt[dstv[e]], 1);
}

// ---------------- hierarchical exclusive scan (+ dis, + cur=0) ----------------
__global__ __launch_bounds__(1024) void k_scan1(const int* __restrict__ cnt,
                                                int* __restrict__ offs,
                                                int* __restrict__ bsum,
                                                float* __restrict__ dis,
                                                int* __restrict__ cur, int n) {
    __shared__ int wsum[16], wbase[16];
    const int tid = threadIdx.x, lane = tid & 63, wv = tid >> 6;
    int i = blockIdx.x * 1024 + tid;
    int v = (i < n) ? cnt[i] : 0;
    int x = v;
    #pragma unroll
    for (int d = 1; d < 64; d <<= 1) {
        int y = __shfl_up(x, d);
        if (lane >= d) x += y;
    }
    if (lane == 63) wsum[wv] = x;
    __syncthreads();
    if (tid < 16) {
        int s = 0;
        for (int j = 0; j < tid; ++j) s += wsum[j];
        wbase[tid] = s;
    }
    __syncthreads();
    if (i < n) {
        offs[i] = wbase[wv] + x - v;            // block-local exclusive
        dis[i]  = rsqrtf((float)(v + 1));
        cur[i]  = 0;
    }
    if (tid == 0) bsum[blockIdx.x] = wbase[15] + wsum[15];
}

__global__ void k_scan2(int* __restrict__ bsum, int nb) {
    int t = threadIdx.x;
    if (nb <= 64) {
        int v = (t < nb) ? bsum[t] : 0;
        int x = v;
        #pragma unroll
        for (int d = 1; d < 64; d <<= 1) {
            int y = __shfl_up(x, d);
            if (t >= d) x += y;
        }
        if (t < nb) bsum[t] = x - v;   // exclusive
    } else if (t == 0) {
        int run = 0;
        for (int j = 0; j < nb; ++j) { int v = bsum[j]; bsum[j] = run; run += v; }
    }
}

// ---------------- CSR fill (offs = local + bsum); also nrm[p] = dis[src] ----------------
__global__ void k_fill(const int* __restrict__ srcv, const int* __restrict__ dstv,
                       const int* __restrict__ offs, const int* __restrict__ bsum,
                       const float* __restrict__ dis, int* __restrict__ cur,
                       int* __restrict__ csr, float* __restrict__ nrm, int E) {
    int e = blockIdx.x * blockDim.x + threadIdx.x;
    if (e < E) {
        int d = dstv[e];
        int s = srcv[e];
        int p = offs[d] + bsum[d >> 10] + atomicAdd(&cur[d], 1);
        csr[p] = s;
        nrm[p] = dis[s];
    }
}

// ---------------- weight transpose + bf16 cast: wt[n][k] = (bf16)W[k][n] ----------------
__global__ void k_wt(const float* __restrict__ W, uint16_t* __restrict__ wt) {
    __shared__ float t[32][33];
    int kb = blockIdx.x * 32, nb = blockIdx.y * 32;
    int tx = threadIdx.x, ty = threadIdx.y;
    #pragma unroll
    for (int i = 0; i < 32; i += 8)
        t[ty + i][tx] = W[(size_t)(kb + ty + i) * D_OUT + nb + tx];
    __syncthreads();
    bf16* o = (bf16*)wt;
    #pragma unroll
    for (int i = 0; i < 32; i += 8)
        o[(size_t)(nb + ty + i) * D_IN + kb + tx] = (bf16)t[tx][ty + i];
}

// ---------------- fused GEMM: H[M][512] = (bf16)X[M][2048](fp32) * W ----------------
// Empirical optimum after 11 structural variants (R2-R13): simple 2-barrier
// single-buffered loop, A staged fp32 via global_load_lds (2 x 32-col halves),
// B bf16 via global_load_lds, cvt fused into LDS read. 48 KB -> 3 blocks/CU.
// XOR involution u^(row&7) on both pre-swizzled source and LDS read.
__global__ __launch_bounds__(256) void k_gemm(const float* __restrict__ X,
                                              const uint16_t* __restrict__ WT,
                                              uint16_t* __restrict__ H, int M) {
    __shared__ float    lsA[2][128 * 32];  // 32 KB
    __shared__ uint16_t lsB[128 * 64];     // 16 KB
    // bijective chunked XCD swizzle: one m-panel's 4 n-blocks -> same XCD
    const int nwg = gridDim.x;
    const int b = blockIdx.x;
    const int q = nwg >> 3, r = nwg & 7;
    const int xcd = b & 7, lo = b >> 3;
    const int g = (xcd < r) ? (xcd * (q + 1) + lo) : (r * (q + 1) + (xcd - r) * q + lo);
    const int m0 = (g >> 2) * 128;
    const int n0 = (g & 3) * 128;
    const int tid = threadIdx.x;
    const int w = tid >> 6, lane = tid & 63;
    const int wr = w >> 1, wc = w & 1;
    const int lr = lane & 15, lk = lane >> 4;

    f32x4 acc[4][4];
    #pragma unroll
    for (int m = 0; m < 4; m++)
        #pragma unroll
        for (int n = 0; n < 4; n++) acc[m][n] = (f32x4)(0.0f);

    const float* aSrc[2][4];
    const uint16_t* bSrc[4];
    #pragma unroll
    for (int j = 0; j < 4; j++) {
        int c = w * 4 + j;
        int uidx = c * 64 + lane;
        int row = uidx >> 3, u = uidx & 7;
        int lrow = row;
        if (m0 + row >= M) lrow = (M - 1) - m0;   // clamp: valid data staged, stores masked
        const float* rbase = X + (size_t)(m0 + lrow) * D_IN;
        #pragma unroll
        for (int h = 0; h < 2; h++)
            aSrc[h][j] = rbase + h * 32 + (u ^ (row & 7)) * 4;
        bSrc[j] = WT + (size_t)(n0 + row) * D_IN + (u ^ (row & 7)) * 8;
    }

    for (int k0 = 0; k0 < D_IN; k0 += 64) {
        #pragma unroll
        for (int h = 0; h < 2; h++)
            #pragma unroll
            for (int j = 0; j < 4; j++)
                __builtin_amdgcn_global_load_lds(GLP(aSrc[h][j] + k0),
                                                 LDSP(lsA[h] + (w * 4 + j) * 256), 16, 0, 0);
        #pragma unroll
        for (int j = 0; j < 4; j++)
            __builtin_amdgcn_global_load_lds(GLP(bSrc[j] + k0),
                                             LDSP(lsB + (w * 4 + j) * 512), 16, 0, 0);
        __syncthreads();

        #pragma unroll
        for (int kk = 0; kk < 2; kk++) {
            bf16x8 aF[4], bF[4];
            #pragma unroll
            for (int m = 0; m < 4; m++) {
                int row = wr * 64 + m * 16 + lr;
                const float* base = lsA[kk] + row * 32;
                f32x4 a0 = *(const f32x4*)(base + (((2 * lk)    ) ^ (row & 7)) * 4);
                f32x4 a1 = *(const f32x4*)(base + (((2 * lk) + 1) ^ (row & 7)) * 4);
                bf16x8 af;
                af[0] = (bf16)a0[0]; af[1] = (bf16)a0[1]; af[2] = (bf16)a0[2]; af[3] = (bf16)a0[3];
                af[4] = (bf16)a1[0]; af[5] = (bf16)a1[1]; af[6] = (bf16)a1[2]; af[7] = (bf16)a1[3];
                aF[m] = af;
            }
            #pragma unroll
            for (int n = 0; n < 4; n++) {
                int row = wc * 64 + n * 16 + lr;
                bF[n] = *(const bf16x8*)((const bf16*)lsB + row * 64 + (((kk * 4 + lk) ^ (row & 7)) * 8));
            }
            #pragma unroll
            for (int m = 0; m < 4; m++)
                #pragma unroll
                for (int n = 0; n < 4; n++)
                    acc[m][n] = __builtin_amdgcn_mfma_f32_16x16x32_bf16(aF[m], bF[n], acc[m][n], 0, 0, 0);
        }
        __syncthreads();
    }

    // epilogue: C/D layout col=lane&15, row=(lane>>4)*4+reg; store bf16
    #pragma unroll
    for (int m = 0; m < 4; m++) {
        int rbase = m0 + wr * 64 + m * 16 + lk * 4;
        #pragma unroll
        for (int n = 0; n < 4; n++) {
            int col = n0 + wc * 64 + n * 16 + lr;
            #pragma unroll
            for (int j = 0; j < 4; j++) {
                int row = rbase + j;
                if (row < M) {
                    bf16 t = (bf16)acc[m][n][j];
                    H[(size_t)row * D_OUT + col] = __builtin_bit_cast(uint16_t, t);
                }
            }
        }
    }
}

// ---------------- aggregation + bias + log_softmax, one wave per node ----------------
// edge loop unrolled x2; nrm[] read linearly (no random dis gather)
__global__ __launch_bounds__(256) void k_agg(const uint16_t* __restrict__ h,
                                             const int* __restrict__ csr,
                                             const float* __restrict__ nrm,
                                             const int* __restrict__ offs,
                                             const int* __restrict__ bsum,
                                             const int* __restrict__ cnt,
                                             const float* __restrict__ dis,
                                             const float* __restrict__ bias,
                                             float* __restrict__ out, int N) {
    const int wv = threadIdx.x >> 6, lane = threadIdx.x & 63;
    const int i = blockIdx.x * 4 + wv;
    if (i >= N) return;
    const float di = dis[i];
    float acc[8];
    {
        u32x4 v = *(const u32x4*)(h + (size_t)i * D_OUT + lane * 8);
        float s2 = di * di;
        #pragma unroll
        for (int k = 0; k < 4; k++) {
            acc[2 * k]     = __builtin_bit_cast(float, v[k] << 16) * s2;
            acc[2 * k + 1] = __builtin_bit_cast(float, v[k] & 0xffff0000u) * s2;
        }
    }
    const int o = offs[i] + bsum[i >> 10], c = cnt[i];
    int e = o;
    for (; e + 2 <= o + c; e += 2) {
        int s0 = csr[e], s1 = csr[e + 1];
        float w0 = di * nrm[e], w1 = di * nrm[e + 1];
        u32x4 v0 = *(const u32x4*)(h + (size_t)s0 * D_OUT + lane * 8);
        u32x4 v1 = *(const u32x4*)(h + (size_t)s1 * D_OUT + lane * 8);
        #pragma unroll
        for (int k = 0; k < 4; k++) {
            acc[2 * k]     += __builtin_bit_cast(float, v0[k] << 16) * w0;
            acc[2 * k + 1] += __builtin_bit_cast(float, v0[k] & 0xffff0000u) * w0;
        }
        #pragma unroll
        for (int k = 0; k < 4; k++) {
            acc[2 * k]     += __builtin_bit_cast(float, v1[k] << 16) * w1;
            acc[2 * k + 1] += __builtin_bit_cast(float, v1[k] & 0xffff0000u) * w1;
        }
    }
    if (e < o + c) {
        int s0 = csr[e];
        float w0 = di * nrm[e];
        u32x4 v0 = *(const u32x4*)(h + (size_t)s0 * D_OUT + lane * 8);
        #pragma unroll
        for (int k = 0; k < 4; k++) {
            acc[2 * k]     += __builtin_bit_cast(float, v0[k] << 16) * w0;
            acc[2 * k + 1] += __builtin_bit_cast(float, v0[k] & 0xffff0000u) * w0;
        }
    }
    {
        const f32x4* bp = (const f32x4*)(bias + lane * 8);
        f32x4 b0 = bp[0], b1 = bp[1];
        #pragma unroll
        for (int k = 0; k < 4; k++) { acc[k] += b0[k]; acc[4 + k] += b1[k]; }
    }
    float mx = acc[0];
    #pragma unroll
    for (int k = 1; k < 8; k++) mx = fmaxf(mx, acc[k]);
    #pragma unroll
    for (int d = 1; d < 64; d <<= 1) mx = fmaxf(mx, __shfl_xor(mx, d));
    float se = 0.f;
    #pragma unroll
    for (int k = 0; k < 8; k++) se += expf(acc[k] - mx);
    #pragma unroll
    for (int d = 1; d < 64; d <<= 1) se += __shfl_xor(se, d);
    float lse = mx + logf(se);
    f32x4 o0, o1;
    #pragma unroll
    for (int k = 0; k < 4; k++) { o0[k] = acc[k] - lse; o1[k] = acc[4 + k] - lse; }
    f32x4* op = (f32x4*)(out + (size_t)i * D_OUT + lane * 8);
    op[0] = o0; op[1] = o1;
}

// ---------------- launch ----------------
extern "C" void kernel_launch(void* const* d_in, const int* in_sizes, int n_in,
                              void* d_out, int out_size, void* d_ws, size_t ws_size,
                              hipStream_t stream) {
    const float* x    = (const float*)d_in[0];
    const int*   ei   = (const int*)d_in[1];
    const float* W    = (const float*)d_in[2];
    const float* bias = (const float*)d_in[3];
    float* out = (float*)d_out;

    const int N = in_sizes[0] / D_IN;     // 50000
    const int E = in_sizes[1] / 2;        // 400000
    const int* srcv = ei;
    const int* dstv = ei + E;

    char* p = (char*)d_ws;
    auto carve = [&](size_t b) { void* r = (void*)p; p += (b + 255) & ~(size_t)255; return r; };
    uint16_t* h    = (uint16_t*)carve((size_t)N * D_OUT * 2);            // 51.2 MB
    uint16_t* wt   = (uint16_t*)carve((size_t)D_OUT * D_IN * 2);         // 2 MB
    int*      cnt  = (int*)carve((size_t)N * 4);
    int*      cur  = (int*)carve((size_t)N * 4);
    float*    dis  = (float*)carve((size_t)N * 4);
    int*      offs = (int*)carve((size_t)N * 4);
    int*      csr  = (int*)carve((size_t)E * 4);
    float*    nrm  = (float*)carve((size_t)E * 4);
    int*      bsum = (int*)carve(1024 * 4);

    hipMemsetAsync(cnt, 0, (size_t)N * 4, stream);

    k_wt<<<dim3(D_IN / 32, D_OUT / 32), dim3(32, 8), 0, stream>>>(W, wt);
    k_count<<<(E + 255) / 256, 256, 0, stream>>>(dstv, cnt, E);
    const int nb = (N + 1023) / 1024;
    k_scan1<<<nb, 1024, 0, stream>>>(cnt, offs, bsum, dis, cur, N);
    k_scan2<<<1, 64, 0, stream>>>(bsum, nb);
    k_fill<<<(E + 255) / 256, 256, 0, stream>>>(srcv, dstv, offs, bsum, dis, cur, csr, nrm, E);

    k_gemm<<<((N + 127) / 128) * 4, 256, 0, stream>>>(x, wt, h, N);

    k_agg<<<(N + 3) / 4, 256, 0, stream>>>(h, csr, nrm, offs, bsum, cnt, dis, bias, out, N);
}